// Round 8
// baseline (524.509 us; speedup 1.0000x reference)
//
#include <hip/hip_runtime.h>
#include <hip/hip_bf16.h>
#include <math.h>

// Problem: B=16, N=1024, D=1024, H=8, HD=128
#define BN 1024
#define DD 1024
#define NB 16
#define NH 8
#define HDIM 128

typedef __attribute__((ext_vector_type(8))) short bf16x8;
typedef __attribute__((ext_vector_type(4))) float f32x4;
typedef __attribute__((ext_vector_type(16))) float f32x16;
typedef __attribute__((ext_vector_type(4))) unsigned short ushort4v;

#define DEV __device__ __forceinline__

DEV unsigned short f2bf(float f) {
  unsigned u = __float_as_uint(f);
  u = (u + 0x7fffu + ((u >> 16) & 1u)) >> 16;  // RNE
  return (unsigned short)u;
}

DEV f32x4 mfma16(bf16x8 a, bf16x8 b, f32x4 c) {
  return __builtin_amdgcn_mfma_f32_16x16x32_bf16(a, b, c, 0, 0, 0);
}

DEV f32x16 mfma32(bf16x8 a, bf16x8 b, f32x16 c) {
  return __builtin_amdgcn_mfma_f32_32x32x16_bf16(a, b, c, 0, 0, 0);
}

// async global->LDS, 16B per lane. LDS dest = wave-uniform base + lane*16.
DEV void async16(const unsigned short* g, unsigned short* l) {
  __builtin_amdgcn_global_load_lds(
      (const __attribute__((address_space(1))) unsigned short*)g,
      (__attribute__((address_space(3))) unsigned short*)l, 16, 0, 0);
}

// packed f32->2xbf16 (RNE) — no builtin on gfx950 (m240), inline asm
DEV unsigned cvtpk(float lo, float hi_) {
  unsigned r;
  asm("v_cvt_pk_bf16_f32 %0, %1, %2" : "=v"(r) : "v"(lo), "v"(hi_));
  return r;
}
// v_permlane32_swap: a' = {a.lo-lanes, b.lo-lanes}, b' = {a.hi-lanes, b.hi-lanes}
DEV void swap32(unsigned& a, unsigned& b) {
  asm volatile("v_permlane32_swap_b32 %0, %1" : "+v"(a), "+v"(b));
}
DEV bf16x8 mk8(unsigned a, unsigned b, unsigned c, unsigned d) {
  union { unsigned u[4]; bf16x8 v; } t;
  t.u[0] = a; t.u[1] = b; t.u[2] = c; t.u[3] = d;
  return t.v;
}

// ---------------------------------------------------------------------------
// K0 (fused prep): conv_x | transpose_qkv | transpose_fc, branched on blockIdx
// ---------------------------------------------------------------------------
__global__ __launch_bounds__(256) void prep_kernel(
    const float* __restrict__ x, const float* __restrict__ Wq,
    const float* __restrict__ Wk, const float* __restrict__ Wv,
    const float* __restrict__ Wfc, unsigned short* __restrict__ x_bf,
    unsigned short* __restrict__ wqkvT, unsigned short* __restrict__ wfcT) {
  __shared__ float tile[32][33];
  const int bx = blockIdx.x, tid = threadIdx.x;
  if (bx < 16384) {
    int i = bx * 256 + tid;
    const float4* p = (const float4*)x;
    float4 v = p[i];
    ushort4v o;
    o[0] = f2bf(v.x); o[1] = f2bf(v.y); o[2] = f2bf(v.z); o[3] = f2bf(v.w);
    *(ushort4v*)(x_bf + (size_t)i * 4) = o;
    return;
  }
  const int tx = tid & 31, ty = tid >> 5;
  if (bx < 19456) {
    int idx = bx - 16384;
    int k0 = (idx & 31) * 32, e0 = ((idx >> 5) & 3) * 32, z = idx >> 7;
    int which = z >> 3, h = z & 7;
    const float* in = (which == 0 ? Wq : (which == 1 ? Wk : Wv)) + (size_t)h * DD * HDIM;
#pragma unroll
    for (int i = 0; i < 4; ++i)
      tile[ty + i * 8][tx] = in[(size_t)(k0 + ty + i * 8) * HDIM + e0 + tx];
    __syncthreads();
    int rowbase = which * 1024 + h * 128 + e0;
#pragma unroll
    for (int i = 0; i < 4; ++i)
      wqkvT[(size_t)(rowbase + ty + i * 8) * DD + k0 + tx] = f2bf(tile[tx][ty + i * 8]);
  } else {
    int idx = bx - 19456;
    int d0 = (idx & 31) * 32, c0 = (idx >> 5) * 32;
#pragma unroll
    for (int i = 0; i < 4; ++i)
      tile[ty + i * 8][tx] = Wfc[(size_t)(d0 + ty + i * 8) * DD + c0 + tx];
    __syncthreads();
#pragma unroll
    for (int i = 0; i < 4; ++i)
      wfcT[(size_t)(c0 + ty + i * 8) * DD + d0 + tx] = f2bf(tile[tx][ty + i * 8]);
  }
}

// ---------------------------------------------------------------------------
// GEMM v6 = R0's known-good mfma16 kernel (0 bank conflicts, proven) with
// ONE change: __launch_bounds__(256,3) -> (256,5).
//
// R7 post-mortem arithmetic: per CU, MFMA-pipe duty ~8%, LDS duty ~24%,
// L2-read ~37%, VALU 18% -- NOTHING saturated => latency-bound on the
// per-K-tile stage->drain->barrier chain with insufficient wave overlap.
// VGPR=68, LDS=32KB => 5 blocks/CU fits EXACTLY (160KB LDS, 340 VGPR/SIMD).
// m97-class kernels could never test this (VGPR 164 caps at 3); ours can.
// +67% independent waves directly attacks a latency-bound regime.
// ---------------------------------------------------------------------------
template <int MODE>
__global__ __launch_bounds__(256, 5) void gemm128_kernel(
    const unsigned short* __restrict__ A, const unsigned short* __restrict__ Bt,
    const float* __restrict__ bias0, const float* __restrict__ bias1,
    const float* __restrict__ bias2, unsigned short* __restrict__ out0,
    unsigned short* __restrict__ out1, unsigned short* __restrict__ out2,
    float* __restrict__ outf) {
  __shared__ unsigned short as[128 * 64];
  __shared__ unsigned short bs[128 * 64];
  const int tid = threadIdx.x;
  const int wave = tid >> 6, lane = tid & 63, quad = lane >> 4, l15 = lane & 15;
  const int wr = wave >> 1, wc = wave & 1;
  const int m0 = (blockIdx.x & 127) << 7, n0 = (blockIdx.x >> 7) << 7;
  f32x4 acc[4][4] = {};

  const int srow = wave * 32 + (lane >> 3);
  const int gch = ((lane & 7) - (lane >> 3)) & 7;
  const unsigned short* ag = A + (size_t)(m0 + srow) * 1024 + gch * 8;
  const unsigned short* bg = Bt + (size_t)(n0 + srow) * 1024 + gch * 8;
  unsigned short* as_w = as + wave * 32 * 64;
  unsigned short* bs_w = bs + wave * 32 * 64;

  for (int kb = 0; kb < 1024; kb += 64) {
#pragma unroll
    for (int i = 0; i < 4; ++i) {
      async16(ag + kb + i * 8 * 1024, as_w + i * 512);
      async16(bg + kb + i * 8 * 1024, bs_w + i * 512);
    }
    __syncthreads();
#pragma unroll
    for (int ks = 0; ks < 2; ++ks) {
      const int sl = ((quad + ks * 4 + l15) & 7) * 8;
      bf16x8 af[4], bfr[4];
#pragma unroll
      for (int mt = 0; mt < 4; ++mt)
        af[mt] = *(const bf16x8*)(as + (wr * 64 + mt * 16 + l15) * 64 + sl);
#pragma unroll
      for (int nt = 0; nt < 4; ++nt)
        bfr[nt] = *(const bf16x8*)(bs + (wc * 64 + nt * 16 + l15) * 64 + sl);
#pragma unroll
      for (int mt = 0; mt < 4; ++mt)
#pragma unroll
        for (int nt = 0; nt < 4; ++nt)
          acc[mt][nt] = mfma16(af[mt], bfr[nt], acc[mt][nt]);
    }
    __syncthreads();
  }

  if constexpr (MODE == 0) {
    const int seg = n0 >> 10;  // 0=q 1=k 2=v
#pragma unroll
    for (int mt = 0; mt < 4; ++mt) {
      int mb = m0 + wr * 64 + mt * 16 + quad * 4;
      int bb = mb >> 10, nn = mb & 1023;
#pragma unroll
      for (int nt = 0; nt < 4; ++nt) {
        int c = n0 + wc * 64 + nt * 16 + l15;
        int cc = c & 1023;
        int h = cc >> 7, e = cc & 127;
        if (seg == 2) {
          float bias = bias2[cc];
          ushort4v pv;
#pragma unroll
          for (int r = 0; r < 4; ++r) pv[r] = f2bf(acc[mt][nt][r] + bias);
          *(ushort4v*)(out2 + ((size_t)(bb * NH + h) * HDIM + e) * BN + nn) = pv;
        } else {
          const float* bp = (seg == 0) ? bias0 : bias1;
          unsigned short* op = (seg == 0) ? out0 : out1;
          float bias = bp[cc];
#pragma unroll
          for (int r = 0; r < 4; ++r)
            op[(((size_t)bb * NH + h) * BN + (nn + r)) * HDIM + e] =
                f2bf(acc[mt][nt][r] + bias);
        }
      }
    }
  } else {
#pragma unroll
    for (int mt = 0; mt < 4; ++mt) {
      int mb = m0 + wr * 64 + mt * 16 + quad * 4;
#pragma unroll
      for (int nt = 0; nt < 4; ++nt) {
        int c = n0 + wc * 64 + nt * 16 + l15;
        float bias = bias0[c];
#pragma unroll
        for (int r = 0; r < 4; ++r)
          outf[(size_t)(mb + r) * DD + c] = acc[mt][nt][r] + bias;
      }
    }
  }
}

// ---------------------------------------------------------------------------
// K4: flash attention v9 (passed R7) — swapped QK^T 32x32, in-reg softmax,
// K+V double-buffered, one barrier/iter, deep-rot V swizzle. Unchanged.
// ---------------------------------------------------------------------------
__global__ __launch_bounds__(256, 2) void flash_attn_kernel(
    const unsigned short* __restrict__ Q, const unsigned short* __restrict__ Kk,
    const unsigned short* __restrict__ Vt, const int* __restrict__ xmask,
    unsigned short* __restrict__ O) {
  __shared__ unsigned short k_s[2][64 * 128];  // 2x16 KB, rot-swizzle mod-16
  __shared__ unsigned short v_s[2][128 * 64];  // 2x16 KB, deep-rot mod-8
  __shared__ float l_s[128];

  const float CL2E = 0.08838834764831845f * 1.44269504088896f;  // SCALE*log2(e)

  const int tid = threadIdx.x;
  const int w = tid >> 6, lane = tid & 63;
  const int l31 = lane & 31, hi = lane >> 5;
  const int lin = blockIdx.x;
  const int bh = lin & 127, qb = lin >> 7;
  const int b = bh >> 3, h = bh & 7;
  const int q0 = qb * 128;
  const unsigned short* qp = Q + ((size_t)bh * BN + q0) * HDIM;
  const unsigned short* kp = Kk + (size_t)bh * BN * HDIM;
  const unsigned short* vp = Vt + (size_t)bh * HDIM * BN;
  const int* xm_b = xmask + b * BN;

  // Q frags (B-operand of 32x32x16): col=q=w*32+l31, d = dk*16 + hi*8 + j
  bf16x8 qf[8];
#pragma unroll
  for (int dk = 0; dk < 8; ++dk)
    qf[dk] = *(const bf16x8*)(qp + (size_t)(w * 32 + l31) * HDIM + dk * 16 + hi * 8);

  const int rm = xm_b[q0 + w * 32 + l31];  // row mask for this lane's q

  // staging lane decomposition
  const int krow = lane >> 4;
  const int vrow = lane >> 3;

  float l_lane = 0.0f;
  f32x16 o_acc[4] = {};  // O[q = crow(r,hi)][e = et*32 + l31]

  // pre-issue tile 0 into buffer 0
#pragma unroll
  for (int i = 0; i < 4; ++i) {
    int rmod = i * 4 + krow;
    int g = ((lane & 15) - rmod) & 15;
    async16(kp + (size_t)(w * 16 + rmod) * HDIM + g * 8, k_s[0] + (w * 16 + i * 4) * 128);
    int e = w * 32 + i * 8 + vrow;
    int vch = ((lane & 7) - vrow - i) & 7;  // deep rotation (i-dependent)
    async16(vp + (size_t)e * BN + vch * 8, v_s[0] + (w * 32 + i * 8) * 64);
  }

  for (int it = 0; it < 16; ++it) {
    const int kb = it * 64;
    const int cur = it & 1, nxt = cur ^ 1;
    // column-mask bits for this tile: bit k = xmask[kb+k]
    const unsigned long long mb = __ballot(xm_b[kb + lane] != 0);
    const unsigned long long mbh = mb >> (4 * hi);

    __syncthreads();  // tile-t DMA complete CU-wide; buffers[nxt] readers done

    // issue DMA(t+1) into the other buffers (wrapped on last iter; harmless)
    {
      const int kn = (kb + 64) & (BN - 1);
      unsigned short* kbn = k_s[nxt];
      unsigned short* vbn = v_s[nxt];
#pragma unroll
      for (int i = 0; i < 4; ++i) {
        int rmod = i * 4 + krow;
        int g = ((lane & 15) - rmod) & 15;
        async16(kp + (size_t)(kn + w * 16 + rmod) * HDIM + g * 8,
                kbn + (w * 16 + i * 4) * 128);
        int e = w * 32 + i * 8 + vrow;
        int vch = ((lane & 7) - vrow - i) & 7;  // deep rotation (i-dependent)
        async16(vp + (size_t)e * BN + kn + vch * 8, vbn + (w * 32 + i * 8) * 64);
      }
    }

    // S^T slices: s0 = k rows [0,32), s1 = [32,64), this wave's 32 q cols
    const unsigned short* kbc = k_s[cur];
    f32x16 s0 = {}, s1 = {};
#pragma unroll
    for (int dk = 0; dk < 8; ++dk) {
      const int cc = (2 * dk + hi + (l31 & 15)) & 15;  // rot-swizzle chunk
      bf16x8 k0 = *(const bf16x8*)(kbc + (size_t)l31 * 128 + cc * 8);
      bf16x8 k1 = *(const bf16x8*)(kbc + (size_t)(32 + l31) * 128 + cc * 8);
      s0 = mfma32(k0, qf[dk], s0);
      s1 = mfma32(k1, qf[dk], s1);
    }

    const unsigned short* vb = v_s[cur];
    const int cbb = (hi + l31 + (l31 >> 3)) & 7;  // deep-rot read base (et-free)

    // ---- half 0: exp(s0) -> pack pa0,pa1 -> PV slots 0,1 (k 0..31)
    {
      float p0[16];
#pragma unroll
      for (int r = 0; r < 16; ++r) {
        const int sh = (r & 3) + 8 * (r >> 2);  // k = sh + 4*hi
        float x0 = s0[r] * CL2E;
        float t0 = ((mbh >> sh) & 1) ? x0 : -60.0f;
        float e0 = rm ? t0 : 0.0f;
        p0[r] = __builtin_amdgcn_exp2f(e0);
        l_lane += p0[r];
      }
      unsigned a0 = cvtpk(p0[0], p0[1]), a1 = cvtpk(p0[2], p0[3]);
      unsigned a2 = cvtpk(p0[4], p0[5]), a3 = cvtpk(p0[6], p0[7]);
      unsigned b0 = cvtpk(p0[8], p0[9]), b1 = cvtpk(p0[10], p0[11]);
      unsigned b2 = cvtpk(p0[12], p0[13]), b3 = cvtpk(p0[14], p0[15]);
      swap32(a0, a2); swap32(a1, a3); swap32(b0, b2); swap32(b1, b3);
      bf16x8 pa0 = mk8(a0, a1, a2, a3);
      bf16x8 pa1 = mk8(b0, b1, b2, b3);
      __builtin_amdgcn_s_setprio(1);
#pragma unroll
      for (int et = 0; et < 4; ++et) {
        const int row = et * 32 + l31;
        bf16x8 v0 = *(const bf16x8*)(vb + (size_t)row * 64 + ((cbb + 0) & 7) * 8);
        bf16x8 v1 = *(const bf16x8*)(vb + (size_t)row * 64 + ((cbb + 2) & 7) * 8);
        o_acc[et] = mfma32(pa0, v0, o_acc[et]);
        o_acc[et] = mfma32(pa1, v1, o_acc[et]);
      }
      __builtin_amdgcn_s_setprio(0);
    }

    // ---- half 1: exp(s1) -> pack pa2,pa3 -> PV slots 2,3 (k 32..63)
    {
      float p1[16];
#pragma unroll
      for (int r = 0; r < 16; ++r) {
        const int sh = (r & 3) + 8 * (r >> 2);
        float x1 = s1[r] * CL2E;
        float t1 = ((mbh >> (sh + 32)) & 1) ? x1 : -60.0f;
        float e1 = rm ? t1 : 0.0f;
        p1[r] = __builtin_amdgcn_exp2f(e1);
        l_lane += p1[r];
      }
      unsigned c0 = cvtpk(p1[0], p1[1]), c1 = cvtpk(p1[2], p1[3]);
      unsigned c2 = cvtpk(p1[4], p1[5]), c3 = cvtpk(p1[6], p1[7]);
      unsigned d0 = cvtpk(p1[8], p1[9]), d1 = cvtpk(p1[10], p1[11]);
      unsigned d2 = cvtpk(p1[12], p1[13]), d3 = cvtpk(p1[14], p1[15]);
      swap32(c0, c2); swap32(c1, c3); swap32(d0, d2); swap32(d1, d3);
      bf16x8 pa2 = mk8(c0, c1, c2, c3);
      bf16x8 pa3 = mk8(d0, d1, d2, d3);
      __builtin_amdgcn_s_setprio(1);
#pragma unroll
      for (int et = 0; et < 4; ++et) {
        const int row = et * 32 + l31;
        bf16x8 v2 = *(const bf16x8*)(vb + (size_t)row * 64 + ((cbb + 4) & 7) * 8);
        bf16x8 v3 = *(const bf16x8*)(vb + (size_t)row * 64 + ((cbb + 6) & 7) * 8);
        o_acc[et] = mfma32(pa2, v2, o_acc[et]);
        o_acc[et] = mfma32(pa3, v3, o_acc[et]);
      }
      __builtin_amdgcn_s_setprio(0);
    }
  }

  // final l per q: lane + lane^32, broadcast via LDS for epilogue
  l_lane += __shfl_xor(l_lane, 32, 64);
  if (hi == 0) l_s[w * 32 + l31] = l_lane;
  __syncthreads();

  // epilogue: O/l, store. lane holds q = crow(r,hi), e = et*32 + l31
#pragma unroll
  for (int r = 0; r < 16; ++r) {
    const int ql = (r & 3) + 8 * (r >> 2) + 4 * hi;
    const float inv = 1.0f / l_s[w * 32 + ql];
    const int row = q0 + w * 32 + ql;
#pragma unroll
    for (int et = 0; et < 4; ++et) {
      const int col = h * HDIM + et * 32 + l31;
      O[((size_t)b * BN + row) * DD + col] = f2bf(o_acc[et][r] * inv);
    }
  }
}

// ---------------------------------------------------------------------------
// Workspace layout (bytes): total ~168 MB
//   x_bf @0 33554432 | wqkvT @33554432 6291456 | wfcT @39845888 2097152
//   q_bf @41943040 | k_bf @75497472 | vT_bf @109051904 | o_bf @142606336 (each 33554432)
// ---------------------------------------------------------------------------
extern "C" void kernel_launch(void* const* d_in, const int* in_sizes, int n_in,
                              void* d_out, int out_size, void* d_ws, size_t ws_size,
                              hipStream_t stream) {
  const float* x = (const float*)d_in[0];
  const int* xmask = (const int*)d_in[1];
  const float* Wq = (const float*)d_in[2];
  const float* bq = (const float*)d_in[3];
  const float* Wk = (const float*)d_in[4];
  const float* bk = (const float*)d_in[5];
  const float* Wv = (const float*)d_in[6];
  const float* bv = (const float*)d_in[7];
  const float* Wfc = (const float*)d_in[8];
  const float* bfc = (const float*)d_in[9];
  float* out = (float*)d_out;

  char* ws = (char*)d_ws;
  unsigned short* x_bf  = (unsigned short*)(ws);
  unsigned short* wqkvT = (unsigned short*)(ws + 33554432);
  unsigned short* wfcT  = (unsigned short*)(ws + 39845888);
  unsigned short* q_bf  = (unsigned short*)(ws + 41943040);
  unsigned short* k_bf  = (unsigned short*)(ws + 75497472);
  unsigned short* vT_bf = (unsigned short*)(ws + 109051904);
  unsigned short* o_bf  = (unsigned short*)(ws + 142606336);

  prep_kernel<<<dim3(20480), dim3(256), 0, stream>>>(x, Wq, Wk, Wv, Wfc, x_bf, wqkvT, wfcT);

  gemm128_kernel<0><<<dim3(3072), dim3(256), 0, stream>>>(
      x_bf, wqkvT, bq, bk, bv, q_bf, k_bf, vT_bf, nullptr);

  flash_attn_kernel<<<dim3(1024), dim3(256), 0, stream>>>(q_bf, k_bf, vT_bf, xmask, o_bf);

  gemm128_kernel<1><<<dim3(1024), dim3(256), 0, stream>>>(
      o_bf, wfcT, bfc, nullptr, nullptr, nullptr, nullptr, nullptr, out);
}

// Round 9
// 430.240 us; speedup vs baseline: 1.2191x; 1.2191x over previous
//
#include <hip/hip_runtime.h>
#include <hip/hip_bf16.h>
#include <math.h>

// Problem: B=16, N=1024, D=1024, H=8, HD=128
#define BN 1024
#define DD 1024
#define NB 16
#define NH 8
#define HDIM 128

typedef __attribute__((ext_vector_type(8))) short bf16x8;
typedef __attribute__((ext_vector_type(4))) float f32x4;
typedef __attribute__((ext_vector_type(16))) float f32x16;
typedef __attribute__((ext_vector_type(4))) unsigned short ushort4v;

#define DEV __device__ __forceinline__

DEV unsigned short f2bf(float f) {
  unsigned u = __float_as_uint(f);
  u = (u + 0x7fffu + ((u >> 16) & 1u)) >> 16;  // RNE
  return (unsigned short)u;
}

DEV f32x4 mfma16(bf16x8 a, bf16x8 b, f32x4 c) {
  return __builtin_amdgcn_mfma_f32_16x16x32_bf16(a, b, c, 0, 0, 0);
}

DEV f32x16 mfma32(bf16x8 a, bf16x8 b, f32x16 c) {
  return __builtin_amdgcn_mfma_f32_32x32x16_bf16(a, b, c, 0, 0, 0);
}

// async global->LDS, 16B per lane. LDS dest = wave-uniform base + lane*16.
DEV void async16(const unsigned short* g, unsigned short* l) {
  __builtin_amdgcn_global_load_lds(
      (const __attribute__((address_space(1))) unsigned short*)g,
      (__attribute__((address_space(3))) unsigned short*)l, 16, 0, 0);
}

// packed f32->2xbf16 (RNE) — no builtin on gfx950 (m240), inline asm
DEV unsigned cvtpk(float lo, float hi_) {
  unsigned r;
  asm("v_cvt_pk_bf16_f32 %0, %1, %2" : "=v"(r) : "v"(lo), "v"(hi_));
  return r;
}
// v_permlane32_swap: a' = {a.lo-lanes, b.lo-lanes}, b' = {a.hi-lanes, b.hi-lanes}
DEV void swap32(unsigned& a, unsigned& b) {
  asm volatile("v_permlane32_swap_b32 %0, %1" : "+v"(a), "+v"(b));
}
DEV bf16x8 mk8(unsigned a, unsigned b, unsigned c, unsigned d) {
  union { unsigned u[4]; bf16x8 v; } t;
  t.u[0] = a; t.u[1] = b; t.u[2] = c; t.u[3] = d;
  return t.v;
}

// ---------------------------------------------------------------------------
// K0 (fused prep): conv_x | transpose_qkv | transpose_fc, branched on blockIdx
// ---------------------------------------------------------------------------
__global__ __launch_bounds__(256) void prep_kernel(
    const float* __restrict__ x, const float* __restrict__ Wq,
    const float* __restrict__ Wk, const float* __restrict__ Wv,
    const float* __restrict__ Wfc, unsigned short* __restrict__ x_bf,
    unsigned short* __restrict__ wqkvT, unsigned short* __restrict__ wfcT) {
  __shared__ float tile[32][33];
  const int bx = blockIdx.x, tid = threadIdx.x;
  if (bx < 16384) {
    int i = bx * 256 + tid;
    const float4* p = (const float4*)x;
    float4 v = p[i];
    ushort4v o;
    o[0] = f2bf(v.x); o[1] = f2bf(v.y); o[2] = f2bf(v.z); o[3] = f2bf(v.w);
    *(ushort4v*)(x_bf + (size_t)i * 4) = o;
    return;
  }
  const int tx = tid & 31, ty = tid >> 5;
  if (bx < 19456) {
    int idx = bx - 16384;
    int k0 = (idx & 31) * 32, e0 = ((idx >> 5) & 3) * 32, z = idx >> 7;
    int which = z >> 3, h = z & 7;
    const float* in = (which == 0 ? Wq : (which == 1 ? Wk : Wv)) + (size_t)h * DD * HDIM;
#pragma unroll
    for (int i = 0; i < 4; ++i)
      tile[ty + i * 8][tx] = in[(size_t)(k0 + ty + i * 8) * HDIM + e0 + tx];
    __syncthreads();
    int rowbase = which * 1024 + h * 128 + e0;
#pragma unroll
    for (int i = 0; i < 4; ++i)
      wqkvT[(size_t)(rowbase + ty + i * 8) * DD + k0 + tx] = f2bf(tile[tx][ty + i * 8]);
  } else {
    int idx = bx - 19456;
    int d0 = (idx & 31) * 32, c0 = (idx >> 5) * 32;
#pragma unroll
    for (int i = 0; i < 4; ++i)
      tile[ty + i * 8][tx] = Wfc[(size_t)(d0 + ty + i * 8) * DD + c0 + tx];
    __syncthreads();
#pragma unroll
    for (int i = 0; i < 4; ++i)
      wfcT[(size_t)(c0 + ty + i * 8) * DD + d0 + tx] = f2bf(tile[tx][ty + i * 8]);
  }
}

// ---------------------------------------------------------------------------
// GEMM v7 = R0's known-good mfma16 kernel with TWO latency-targeted changes:
//  1. __launch_bounds__(256,4): 4 blocks/CU (VGPR cap 128 >= 68 needed -> no
//     spill; R8's (256,5) squeezed VGPR to 48 and spilled the accumulator:
//     WRITE_SIZE 116->513MB. (256,4) is the clean occupancy test.)
//  2. XCD-aware bijective block swizzle (T1): consecutive blocks sharing a
//     B-panel currently scatter across 8 XCDs -> every L2 replicates every
//     panel -> staging DMA eats L3/HBM latency. Chunking gives each XCD
//     3 (MODE 0) / 1 (MODE 1) contiguous B-panels (768/256KB, L2-resident).
//     nwg = 3072 / 1024, both % 8 == 0 -> simple chunk swizzle is bijective.
// ---------------------------------------------------------------------------
template <int MODE>
__global__ __launch_bounds__(256, 4) void gemm128_kernel(
    const unsigned short* __restrict__ A, const unsigned short* __restrict__ Bt,
    const float* __restrict__ bias0, const float* __restrict__ bias1,
    const float* __restrict__ bias2, unsigned short* __restrict__ out0,
    unsigned short* __restrict__ out1, unsigned short* __restrict__ out2,
    float* __restrict__ outf) {
  __shared__ unsigned short as[128 * 64];
  __shared__ unsigned short bs[128 * 64];
  const int tid = threadIdx.x;
  const int wave = tid >> 6, lane = tid & 63, quad = lane >> 4, l15 = lane & 15;
  const int wr = wave >> 1, wc = wave & 1;

  // XCD-aware bijective swizzle: xcd = bid&7 gets chunk [xcd*CPX, ...)
  constexpr int CPX = (MODE == 0) ? 384 : 128;  // nwg/8
  const int wg = (blockIdx.x & 7) * CPX + (blockIdx.x >> 3);
  const int m0 = (wg & 127) << 7, n0 = (wg >> 7) << 7;
  f32x4 acc[4][4] = {};

  const int srow = wave * 32 + (lane >> 3);
  const int gch = ((lane & 7) - (lane >> 3)) & 7;
  const unsigned short* ag = A + (size_t)(m0 + srow) * 1024 + gch * 8;
  const unsigned short* bg = Bt + (size_t)(n0 + srow) * 1024 + gch * 8;
  unsigned short* as_w = as + wave * 32 * 64;
  unsigned short* bs_w = bs + wave * 32 * 64;

  for (int kb = 0; kb < 1024; kb += 64) {
#pragma unroll
    for (int i = 0; i < 4; ++i) {
      async16(ag + kb + i * 8 * 1024, as_w + i * 512);
      async16(bg + kb + i * 8 * 1024, bs_w + i * 512);
    }
    __syncthreads();
#pragma unroll
    for (int ks = 0; ks < 2; ++ks) {
      const int sl = ((quad + ks * 4 + l15) & 7) * 8;
      bf16x8 af[4], bfr[4];
#pragma unroll
      for (int mt = 0; mt < 4; ++mt)
        af[mt] = *(const bf16x8*)(as + (wr * 64 + mt * 16 + l15) * 64 + sl);
#pragma unroll
      for (int nt = 0; nt < 4; ++nt)
        bfr[nt] = *(const bf16x8*)(bs + (wc * 64 + nt * 16 + l15) * 64 + sl);
#pragma unroll
      for (int mt = 0; mt < 4; ++mt)
#pragma unroll
        for (int nt = 0; nt < 4; ++nt)
          acc[mt][nt] = mfma16(af[mt], bfr[nt], acc[mt][nt]);
    }
    __syncthreads();
  }

  if constexpr (MODE == 0) {
    const int seg = n0 >> 10;  // 0=q 1=k 2=v
#pragma unroll
    for (int mt = 0; mt < 4; ++mt) {
      int mb = m0 + wr * 64 + mt * 16 + quad * 4;
      int bb = mb >> 10, nn = mb & 1023;
#pragma unroll
      for (int nt = 0; nt < 4; ++nt) {
        int c = n0 + wc * 64 + nt * 16 + l15;
        int cc = c & 1023;
        int h = cc >> 7, e = cc & 127;
        if (seg == 2) {
          float bias = bias2[cc];
          ushort4v pv;
#pragma unroll
          for (int r = 0; r < 4; ++r) pv[r] = f2bf(acc[mt][nt][r] + bias);
          *(ushort4v*)(out2 + ((size_t)(bb * NH + h) * HDIM + e) * BN + nn) = pv;
        } else {
          const float* bp = (seg == 0) ? bias0 : bias1;
          unsigned short* op = (seg == 0) ? out0 : out1;
          float bias = bp[cc];
#pragma unroll
          for (int r = 0; r < 4; ++r)
            op[(((size_t)bb * NH + h) * BN + (nn + r)) * HDIM + e] =
                f2bf(acc[mt][nt][r] + bias);
        }
      }
    }
  } else {
#pragma unroll
    for (int mt = 0; mt < 4; ++mt) {
      int mb = m0 + wr * 64 + mt * 16 + quad * 4;
#pragma unroll
      for (int nt = 0; nt < 4; ++nt) {
        int c = n0 + wc * 64 + nt * 16 + l15;
        float bias = bias0[c];
#pragma unroll
        for (int r = 0; r < 4; ++r)
          outf[(size_t)(mb + r) * DD + c] = acc[mt][nt][r] + bias;
      }
    }
  }
}

// ---------------------------------------------------------------------------
// K4: flash attention v9 (passed R7/R8) — swapped QK^T 32x32, in-reg softmax,
// K+V double-buffered, one barrier/iter, deep-rot V swizzle. Unchanged.
// ---------------------------------------------------------------------------
__global__ __launch_bounds__(256, 2) void flash_attn_kernel(
    const unsigned short* __restrict__ Q, const unsigned short* __restrict__ Kk,
    const unsigned short* __restrict__ Vt, const int* __restrict__ xmask,
    unsigned short* __restrict__ O) {
  __shared__ unsigned short k_s[2][64 * 128];  // 2x16 KB, rot-swizzle mod-16
  __shared__ unsigned short v_s[2][128 * 64];  // 2x16 KB, deep-rot mod-8
  __shared__ float l_s[128];

  const float CL2E = 0.08838834764831845f * 1.44269504088896f;  // SCALE*log2(e)

  const int tid = threadIdx.x;
  const int w = tid >> 6, lane = tid & 63;
  const int l31 = lane & 31, hi = lane >> 5;
  const int lin = blockIdx.x;
  const int bh = lin & 127, qb = lin >> 7;
  const int b = bh >> 3, h = bh & 7;
  const int q0 = qb * 128;
  const unsigned short* qp = Q + ((size_t)bh * BN + q0) * HDIM;
  const unsigned short* kp = Kk + (size_t)bh * BN * HDIM;
  const unsigned short* vp = Vt + (size_t)bh * HDIM * BN;
  const int* xm_b = xmask + b * BN;

  // Q frags (B-operand of 32x32x16): col=q=w*32+l31, d = dk*16 + hi*8 + j
  bf16x8 qf[8];
#pragma unroll
  for (int dk = 0; dk < 8; ++dk)
    qf[dk] = *(const bf16x8*)(qp + (size_t)(w * 32 + l31) * HDIM + dk * 16 + hi * 8);

  const int rm = xm_b[q0 + w * 32 + l31];  // row mask for this lane's q

  // staging lane decomposition
  const int krow = lane >> 4;
  const int vrow = lane >> 3;

  float l_lane = 0.0f;
  f32x16 o_acc[4] = {};  // O[q = crow(r,hi)][e = et*32 + l31]

  // pre-issue tile 0 into buffer 0
#pragma unroll
  for (int i = 0; i < 4; ++i) {
    int rmod = i * 4 + krow;
    int g = ((lane & 15) - rmod) & 15;
    async16(kp + (size_t)(w * 16 + rmod) * HDIM + g * 8, k_s[0] + (w * 16 + i * 4) * 128);
    int e = w * 32 + i * 8 + vrow;
    int vch = ((lane & 7) - vrow - i) & 7;  // deep rotation (i-dependent)
    async16(vp + (size_t)e * BN + vch * 8, v_s[0] + (w * 32 + i * 8) * 64);
  }

  for (int it = 0; it < 16; ++it) {
    const int kb = it * 64;
    const int cur = it & 1, nxt = cur ^ 1;
    // column-mask bits for this tile: bit k = xmask[kb+k]
    const unsigned long long mb = __ballot(xm_b[kb + lane] != 0);
    const unsigned long long mbh = mb >> (4 * hi);

    __syncthreads();  // tile-t DMA complete CU-wide; buffers[nxt] readers done

    // issue DMA(t+1) into the other buffers (wrapped on last iter; harmless)
    {
      const int kn = (kb + 64) & (BN - 1);
      unsigned short* kbn = k_s[nxt];
      unsigned short* vbn = v_s[nxt];
#pragma unroll
      for (int i = 0; i < 4; ++i) {
        int rmod = i * 4 + krow;
        int g = ((lane & 15) - rmod) & 15;
        async16(kp + (size_t)(kn + w * 16 + rmod) * HDIM + g * 8,
                kbn + (w * 16 + i * 4) * 128);
        int e = w * 32 + i * 8 + vrow;
        int vch = ((lane & 7) - vrow - i) & 7;  // deep rotation (i-dependent)
        async16(vp + (size_t)e * BN + kn + vch * 8, vbn + (w * 32 + i * 8) * 64);
      }
    }

    // S^T slices: s0 = k rows [0,32), s1 = [32,64), this wave's 32 q cols
    const unsigned short* kbc = k_s[cur];
    f32x16 s0 = {}, s1 = {};
#pragma unroll
    for (int dk = 0; dk < 8; ++dk) {
      const int cc = (2 * dk + hi + (l31 & 15)) & 15;  // rot-swizzle chunk
      bf16x8 k0 = *(const bf16x8*)(kbc + (size_t)l31 * 128 + cc * 8);
      bf16x8 k1 = *(const bf16x8*)(kbc + (size_t)(32 + l31) * 128 + cc * 8);
      s0 = mfma32(k0, qf[dk], s0);
      s1 = mfma32(k1, qf[dk], s1);
    }

    const unsigned short* vb = v_s[cur];
    const int cbb = (hi + l31 + (l31 >> 3)) & 7;  // deep-rot read base (et-free)

    // ---- half 0: exp(s0) -> pack pa0,pa1 -> PV slots 0,1 (k 0..31)
    {
      float p0[16];
#pragma unroll
      for (int r = 0; r < 16; ++r) {
        const int sh = (r & 3) + 8 * (r >> 2);  // k = sh + 4*hi
        float x0 = s0[r] * CL2E;
        float t0 = ((mbh >> sh) & 1) ? x0 : -60.0f;
        float e0 = rm ? t0 : 0.0f;
        p0[r] = __builtin_amdgcn_exp2f(e0);
        l_lane += p0[r];
      }
      unsigned a0 = cvtpk(p0[0], p0[1]), a1 = cvtpk(p0[2], p0[3]);
      unsigned a2 = cvtpk(p0[4], p0[5]), a3 = cvtpk(p0[6], p0[7]);
      unsigned b0 = cvtpk(p0[8], p0[9]), b1 = cvtpk(p0[10], p0[11]);
      unsigned b2 = cvtpk(p0[12], p0[13]), b3 = cvtpk(p0[14], p0[15]);
      swap32(a0, a2); swap32(a1, a3); swap32(b0, b2); swap32(b1, b3);
      bf16x8 pa0 = mk8(a0, a1, a2, a3);
      bf16x8 pa1 = mk8(b0, b1, b2, b3);
      __builtin_amdgcn_s_setprio(1);
#pragma unroll
      for (int et = 0; et < 4; ++et) {
        const int row = et * 32 + l31;
        bf16x8 v0 = *(const bf16x8*)(vb + (size_t)row * 64 + ((cbb + 0) & 7) * 8);
        bf16x8 v1 = *(const bf16x8*)(vb + (size_t)row * 64 + ((cbb + 2) & 7) * 8);
        o_acc[et] = mfma32(pa0, v0, o_acc[et]);
        o_acc[et] = mfma32(pa1, v1, o_acc[et]);
      }
      __builtin_amdgcn_s_setprio(0);
    }

    // ---- half 1: exp(s1) -> pack pa2,pa3 -> PV slots 2,3 (k 32..63)
    {
      float p1[16];
#pragma unroll
      for (int r = 0; r < 16; ++r) {
        const int sh = (r & 3) + 8 * (r >> 2);
        float x1 = s1[r] * CL2E;
        float t1 = ((mbh >> (sh + 32)) & 1) ? x1 : -60.0f;
        float e1 = rm ? t1 : 0.0f;
        p1[r] = __builtin_amdgcn_exp2f(e1);
        l_lane += p1[r];
      }
      unsigned c0 = cvtpk(p1[0], p1[1]), c1 = cvtpk(p1[2], p1[3]);
      unsigned c2 = cvtpk(p1[4], p1[5]), c3 = cvtpk(p1[6], p1[7]);
      unsigned d0 = cvtpk(p1[8], p1[9]), d1 = cvtpk(p1[10], p1[11]);
      unsigned d2 = cvtpk(p1[12], p1[13]), d3 = cvtpk(p1[14], p1[15]);
      swap32(c0, c2); swap32(c1, c3); swap32(d0, d2); swap32(d1, d3);
      bf16x8 pa2 = mk8(c0, c1, c2, c3);
      bf16x8 pa3 = mk8(d0, d1, d2, d3);
      __builtin_amdgcn_s_setprio(1);
#pragma unroll
      for (int et = 0; et < 4; ++et) {
        const int row = et * 32 + l31;
        bf16x8 v2 = *(const bf16x8*)(vb + (size_t)row * 64 + ((cbb + 4) & 7) * 8);
        bf16x8 v3 = *(const bf16x8*)(vb + (size_t)row * 64 + ((cbb + 6) & 7) * 8);
        o_acc[et] = mfma32(pa2, v2, o_acc[et]);
        o_acc[et] = mfma32(pa3, v3, o_acc[et]);
      }
      __builtin_amdgcn_s_setprio(0);
    }
  }

  // final l per q: lane + lane^32, broadcast via LDS for epilogue
  l_lane += __shfl_xor(l_lane, 32, 64);
  if (hi == 0) l_s[w * 32 + l31] = l_lane;
  __syncthreads();

  // epilogue: O/l, store. lane holds q = crow(r,hi), e = et*32 + l31
#pragma unroll
  for (int r = 0; r < 16; ++r) {
    const int ql = (r & 3) + 8 * (r >> 2) + 4 * hi;
    const float inv = 1.0f / l_s[w * 32 + ql];
    const int row = q0 + w * 32 + ql;
#pragma unroll
    for (int et = 0; et < 4; ++et) {
      const int col = h * HDIM + et * 32 + l31;
      O[((size_t)b * BN + row) * DD + col] = f2bf(o_acc[et][r] * inv);
    }
  }
}

// ---------------------------------------------------------------------------
// Workspace layout (bytes): total ~168 MB
//   x_bf @0 33554432 | wqkvT @33554432 6291456 | wfcT @39845888 2097152
//   q_bf @41943040 | k_bf @75497472 | vT_bf @109051904 | o_bf @142606336 (each 33554432)
// ---------------------------------------------------------------------------
extern "C" void kernel_launch(void* const* d_in, const int* in_sizes, int n_in,
                              void* d_out, int out_size, void* d_ws, size_t ws_size,
                              hipStream_t stream) {
  const float* x = (const float*)d_in[0];
  const int* xmask = (const int*)d_in[1];
  const float* Wq = (const float*)d_in[2];
  const float* bq = (const float*)d_in[3];
  const float* Wk = (const float*)d_in[4];
  const float* bk = (const float*)d_in[5];
  const float* Wv = (const float*)d_in[6];
  const float* bv = (const float*)d_in[7];
  const float* Wfc = (const float*)d_in[8];
  const float* bfc = (const float*)d_in[9];
  float* out = (float*)d_out;

  char* ws = (char*)d_ws;
  unsigned short* x_bf  = (unsigned short*)(ws);
  unsigned short* wqkvT = (unsigned short*)(ws + 33554432);
  unsigned short* wfcT  = (unsigned short*)(ws + 39845888);
  unsigned short* q_bf  = (unsigned short*)(ws + 41943040);
  unsigned short* k_bf  = (unsigned short*)(ws + 75497472);
  unsigned short* vT_bf = (unsigned short*)(ws + 109051904);
  unsigned short* o_bf  = (unsigned short*)(ws + 142606336);

  prep_kernel<<<dim3(20480), dim3(256), 0, stream>>>(x, Wq, Wk, Wv, Wfc, x_bf, wqkvT, wfcT);

  gemm128_kernel<0><<<dim3(3072), dim3(256), 0, stream>>>(
      x_bf, wqkvT, bq, bk, bv, q_bf, k_bf, vT_bf, nullptr);

  flash_attn_kernel<<<dim3(1024), dim3(256), 0, stream>>>(q_bf, k_bf, vT_bf, xmask, o_bf);

  gemm128_kernel<1><<<dim3(1024), dim3(256), 0, stream>>>(
      o_bf, wfcT, bfc, nullptr, nullptr, nullptr, nullptr, nullptr, out);
}

// Round 10
// 389.653 us; speedup vs baseline: 1.3461x; 1.1042x over previous
//
#include <hip/hip_runtime.h>
#include <hip/hip_bf16.h>
#include <math.h>

// Problem: B=16, N=1024, D=1024, H=8, HD=128
#define BN 1024
#define DD 1024
#define NB 16
#define NH 8
#define HDIM 128

typedef __attribute__((ext_vector_type(8))) short bf16x8;
typedef __attribute__((ext_vector_type(4))) float f32x4;
typedef __attribute__((ext_vector_type(16))) float f32x16;
typedef __attribute__((ext_vector_type(4))) unsigned short ushort4v;

#define DEV __device__ __forceinline__

DEV unsigned short f2bf(float f) {
  unsigned u = __float_as_uint(f);
  u = (u + 0x7fffu + ((u >> 16) & 1u)) >> 16;  // RNE
  return (unsigned short)u;
}

DEV f32x4 mfma16(bf16x8 a, bf16x8 b, f32x4 c) {
  return __builtin_amdgcn_mfma_f32_16x16x32_bf16(a, b, c, 0, 0, 0);
}

DEV f32x16 mfma32(bf16x8 a, bf16x8 b, f32x16 c) {
  return __builtin_amdgcn_mfma_f32_32x32x16_bf16(a, b, c, 0, 0, 0);
}

// async global->LDS, 16B per lane. LDS dest = wave-uniform base + lane*16.
DEV void async16(const unsigned short* g, unsigned short* l) {
  __builtin_amdgcn_global_load_lds(
      (const __attribute__((address_space(1))) unsigned short*)g,
      (__attribute__((address_space(3))) unsigned short*)l, 16, 0, 0);
}

// packed f32->2xbf16 (RNE) — no builtin on gfx950 (m240), inline asm
DEV unsigned cvtpk(float lo, float hi_) {
  unsigned r;
  asm("v_cvt_pk_bf16_f32 %0, %1, %2" : "=v"(r) : "v"(lo), "v"(hi_));
  return r;
}
// v_permlane32_swap: a' = {a.lo-lanes, b.lo-lanes}, b' = {a.hi-lanes, b.hi-lanes}
DEV void swap32(unsigned& a, unsigned& b) {
  asm volatile("v_permlane32_swap_b32 %0, %1" : "+v"(a), "+v"(b));
}
DEV bf16x8 mk8(unsigned a, unsigned b, unsigned c, unsigned d) {
  union { unsigned u[4]; bf16x8 v; } t;
  t.u[0] = a; t.u[1] = b; t.u[2] = c; t.u[3] = d;
  return t.v;
}

// ---------------------------------------------------------------------------
// K0 (fused prep): conv_x | transpose_qkv | transpose_fc, branched on blockIdx
// ---------------------------------------------------------------------------
__global__ __launch_bounds__(256) void prep_kernel(
    const float* __restrict__ x, const float* __restrict__ Wq,
    const float* __restrict__ Wk, const float* __restrict__ Wv,
    const float* __restrict__ Wfc, unsigned short* __restrict__ x_bf,
    unsigned short* __restrict__ wqkvT, unsigned short* __restrict__ wfcT) {
  __shared__ float tile[32][33];
  const int bx = blockIdx.x, tid = threadIdx.x;
  if (bx < 16384) {
    int i = bx * 256 + tid;
    const float4* p = (const float4*)x;
    float4 v = p[i];
    ushort4v o;
    o[0] = f2bf(v.x); o[1] = f2bf(v.y); o[2] = f2bf(v.z); o[3] = f2bf(v.w);
    *(ushort4v*)(x_bf + (size_t)i * 4) = o;
    return;
  }
  const int tx = tid & 31, ty = tid >> 5;
  if (bx < 19456) {
    int idx = bx - 16384;
    int k0 = (idx & 31) * 32, e0 = ((idx >> 5) & 3) * 32, z = idx >> 7;
    int which = z >> 3, h = z & 7;
    const float* in = (which == 0 ? Wq : (which == 1 ? Wk : Wv)) + (size_t)h * DD * HDIM;
#pragma unroll
    for (int i = 0; i < 4; ++i)
      tile[ty + i * 8][tx] = in[(size_t)(k0 + ty + i * 8) * HDIM + e0 + tx];
    __syncthreads();
    int rowbase = which * 1024 + h * 128 + e0;
#pragma unroll
    for (int i = 0; i < 4; ++i)
      wqkvT[(size_t)(rowbase + ty + i * 8) * DD + k0 + tx] = f2bf(tile[tx][ty + i * 8]);
  } else {
    int idx = bx - 19456;
    int d0 = (idx & 31) * 32, c0 = (idx >> 5) * 32;
#pragma unroll
    for (int i = 0; i < 4; ++i)
      tile[ty + i * 8][tx] = Wfc[(size_t)(d0 + ty + i * 8) * DD + c0 + tx];
    __syncthreads();
#pragma unroll
    for (int i = 0; i < 4; ++i)
      wfcT[(size_t)(c0 + ty + i * 8) * DD + d0 + tx] = f2bf(tile[tx][ty + i * 8]);
  }
}

// ---------------------------------------------------------------------------
// GEMM v8 = R0's proven kernel (mfma16, linear blockIdx, 0-conflict swizzle)
// with EXACTLY ONE change: __launch_bounds__(256,3) -> (256,4).
//
// R9 falsified the XCD chunk swizzle (FETCH 126->404MB: consecutive wg per
// XCD walk ALL 128 m-tiles -> 32MB A working set per L2 -> thrash; default
// round-robin keeps it at ~16 tiles = 4MB). Reverted to linear blockIdx.
// R9 also proved (256,4) compiles clean: VGPR 64, no scratch (R8's (256,5)
// spilled at VGPR 48). This round is the pure occupancy A/B:
// 3 -> 4 blocks/CU, +33% independent waves against the latency chain.
// ---------------------------------------------------------------------------
template <int MODE>
__global__ __launch_bounds__(256, 4) void gemm128_kernel(
    const unsigned short* __restrict__ A, const unsigned short* __restrict__ Bt,
    const float* __restrict__ bias0, const float* __restrict__ bias1,
    const float* __restrict__ bias2, unsigned short* __restrict__ out0,
    unsigned short* __restrict__ out1, unsigned short* __restrict__ out2,
    float* __restrict__ outf) {
  __shared__ unsigned short as[128 * 64];
  __shared__ unsigned short bs[128 * 64];
  const int tid = threadIdx.x;
  const int wave = tid >> 6, lane = tid & 63, quad = lane >> 4, l15 = lane & 15;
  const int wr = wave >> 1, wc = wave & 1;
  const int m0 = (blockIdx.x & 127) << 7, n0 = (blockIdx.x >> 7) << 7;
  f32x4 acc[4][4] = {};

  const int srow = wave * 32 + (lane >> 3);
  const int gch = ((lane & 7) - (lane >> 3)) & 7;
  const unsigned short* ag = A + (size_t)(m0 + srow) * 1024 + gch * 8;
  const unsigned short* bg = Bt + (size_t)(n0 + srow) * 1024 + gch * 8;
  unsigned short* as_w = as + wave * 32 * 64;
  unsigned short* bs_w = bs + wave * 32 * 64;

  for (int kb = 0; kb < 1024; kb += 64) {
#pragma unroll
    for (int i = 0; i < 4; ++i) {
      async16(ag + kb + i * 8 * 1024, as_w + i * 512);
      async16(bg + kb + i * 8 * 1024, bs_w + i * 512);
    }
    __syncthreads();
#pragma unroll
    for (int ks = 0; ks < 2; ++ks) {
      const int sl = ((quad + ks * 4 + l15) & 7) * 8;
      bf16x8 af[4], bfr[4];
#pragma unroll
      for (int mt = 0; mt < 4; ++mt)
        af[mt] = *(const bf16x8*)(as + (wr * 64 + mt * 16 + l15) * 64 + sl);
#pragma unroll
      for (int nt = 0; nt < 4; ++nt)
        bfr[nt] = *(const bf16x8*)(bs + (wc * 64 + nt * 16 + l15) * 64 + sl);
#pragma unroll
      for (int mt = 0; mt < 4; ++mt)
#pragma unroll
        for (int nt = 0; nt < 4; ++nt)
          acc[mt][nt] = mfma16(af[mt], bfr[nt], acc[mt][nt]);
    }
    __syncthreads();
  }

  if constexpr (MODE == 0) {
    const int seg = n0 >> 10;  // 0=q 1=k 2=v
#pragma unroll
    for (int mt = 0; mt < 4; ++mt) {
      int mb = m0 + wr * 64 + mt * 16 + quad * 4;
      int bb = mb >> 10, nn = mb & 1023;
#pragma unroll
      for (int nt = 0; nt < 4; ++nt) {
        int c = n0 + wc * 64 + nt * 16 + l15;
        int cc = c & 1023;
        int h = cc >> 7, e = cc & 127;
        if (seg == 2) {
          float bias = bias2[cc];
          ushort4v pv;
#pragma unroll
          for (int r = 0; r < 4; ++r) pv[r] = f2bf(acc[mt][nt][r] + bias);
          *(ushort4v*)(out2 + ((size_t)(bb * NH + h) * HDIM + e) * BN + nn) = pv;
        } else {
          const float* bp = (seg == 0) ? bias0 : bias1;
          unsigned short* op = (seg == 0) ? out0 : out1;
          float bias = bp[cc];
#pragma unroll
          for (int r = 0; r < 4; ++r)
            op[(((size_t)bb * NH + h) * BN + (nn + r)) * HDIM + e] =
                f2bf(acc[mt][nt][r] + bias);
        }
      }
    }
  } else {
#pragma unroll
    for (int mt = 0; mt < 4; ++mt) {
      int mb = m0 + wr * 64 + mt * 16 + quad * 4;
#pragma unroll
      for (int nt = 0; nt < 4; ++nt) {
        int c = n0 + wc * 64 + nt * 16 + l15;
        float bias = bias0[c];
#pragma unroll
        for (int r = 0; r < 4; ++r)
          outf[(size_t)(mb + r) * DD + c] = acc[mt][nt][r] + bias;
      }
    }
  }
}

// ---------------------------------------------------------------------------
// K4: flash attention v9 (passed R7/R8/R9) — swapped QK^T 32x32, in-reg
// softmax, K+V double-buffered, one barrier/iter, deep-rot V swizzle.
// ---------------------------------------------------------------------------
__global__ __launch_bounds__(256, 2) void flash_attn_kernel(
    const unsigned short* __restrict__ Q, const unsigned short* __restrict__ Kk,
    const unsigned short* __restrict__ Vt, const int* __restrict__ xmask,
    unsigned short* __restrict__ O) {
  __shared__ unsigned short k_s[2][64 * 128];  // 2x16 KB, rot-swizzle mod-16
  __shared__ unsigned short v_s[2][128 * 64];  // 2x16 KB, deep-rot mod-8
  __shared__ float l_s[128];

  const float CL2E = 0.08838834764831845f * 1.44269504088896f;  // SCALE*log2(e)

  const int tid = threadIdx.x;
  const int w = tid >> 6, lane = tid & 63;
  const int l31 = lane & 31, hi = lane >> 5;
  const int lin = blockIdx.x;
  const int bh = lin & 127, qb = lin >> 7;
  const int b = bh >> 3, h = bh & 7;
  const int q0 = qb * 128;
  const unsigned short* qp = Q + ((size_t)bh * BN + q0) * HDIM;
  const unsigned short* kp = Kk + (size_t)bh * BN * HDIM;
  const unsigned short* vp = Vt + (size_t)bh * HDIM * BN;
  const int* xm_b = xmask + b * BN;

  // Q frags (B-operand of 32x32x16): col=q=w*32+l31, d = dk*16 + hi*8 + j
  bf16x8 qf[8];
#pragma unroll
  for (int dk = 0; dk < 8; ++dk)
    qf[dk] = *(const bf16x8*)(qp + (size_t)(w * 32 + l31) * HDIM + dk * 16 + hi * 8);

  const int rm = xm_b[q0 + w * 32 + l31];  // row mask for this lane's q

  // staging lane decomposition
  const int krow = lane >> 4;
  const int vrow = lane >> 3;

  float l_lane = 0.0f;
  f32x16 o_acc[4] = {};  // O[q = crow(r,hi)][e = et*32 + l31]

  // pre-issue tile 0 into buffer 0
#pragma unroll
  for (int i = 0; i < 4; ++i) {
    int rmod = i * 4 + krow;
    int g = ((lane & 15) - rmod) & 15;
    async16(kp + (size_t)(w * 16 + rmod) * HDIM + g * 8, k_s[0] + (w * 16 + i * 4) * 128);
    int e = w * 32 + i * 8 + vrow;
    int vch = ((lane & 7) - vrow - i) & 7;  // deep rotation (i-dependent)
    async16(vp + (size_t)e * BN + vch * 8, v_s[0] + (w * 32 + i * 8) * 64);
  }

  for (int it = 0; it < 16; ++it) {
    const int kb = it * 64;
    const int cur = it & 1, nxt = cur ^ 1;
    // column-mask bits for this tile: bit k = xmask[kb+k]
    const unsigned long long mb = __ballot(xm_b[kb + lane] != 0);
    const unsigned long long mbh = mb >> (4 * hi);

    __syncthreads();  // tile-t DMA complete CU-wide; buffers[nxt] readers done

    // issue DMA(t+1) into the other buffers (wrapped on last iter; harmless)
    {
      const int kn = (kb + 64) & (BN - 1);
      unsigned short* kbn = k_s[nxt];
      unsigned short* vbn = v_s[nxt];
#pragma unroll
      for (int i = 0; i < 4; ++i) {
        int rmod = i * 4 + krow;
        int g = ((lane & 15) - rmod) & 15;
        async16(kp + (size_t)(kn + w * 16 + rmod) * HDIM + g * 8,
                kbn + (w * 16 + i * 4) * 128);
        int e = w * 32 + i * 8 + vrow;
        int vch = ((lane & 7) - vrow - i) & 7;  // deep rotation (i-dependent)
        async16(vp + (size_t)e * BN + kn + vch * 8, vbn + (w * 32 + i * 8) * 64);
      }
    }

    // S^T slices: s0 = k rows [0,32), s1 = [32,64), this wave's 32 q cols
    const unsigned short* kbc = k_s[cur];
    f32x16 s0 = {}, s1 = {};
#pragma unroll
    for (int dk = 0; dk < 8; ++dk) {
      const int cc = (2 * dk + hi + (l31 & 15)) & 15;  // rot-swizzle chunk
      bf16x8 k0 = *(const bf16x8*)(kbc + (size_t)l31 * 128 + cc * 8);
      bf16x8 k1 = *(const bf16x8*)(kbc + (size_t)(32 + l31) * 128 + cc * 8);
      s0 = mfma32(k0, qf[dk], s0);
      s1 = mfma32(k1, qf[dk], s1);
    }

    const unsigned short* vb = v_s[cur];
    const int cbb = (hi + l31 + (l31 >> 3)) & 7;  // deep-rot read base (et-free)

    // ---- half 0: exp(s0) -> pack pa0,pa1 -> PV slots 0,1 (k 0..31)
    {
      float p0[16];
#pragma unroll
      for (int r = 0; r < 16; ++r) {
        const int sh = (r & 3) + 8 * (r >> 2);  // k = sh + 4*hi
        float x0 = s0[r] * CL2E;
        float t0 = ((mbh >> sh) & 1) ? x0 : -60.0f;
        float e0 = rm ? t0 : 0.0f;
        p0[r] = __builtin_amdgcn_exp2f(e0);
        l_lane += p0[r];
      }
      unsigned a0 = cvtpk(p0[0], p0[1]), a1 = cvtpk(p0[2], p0[3]);
      unsigned a2 = cvtpk(p0[4], p0[5]), a3 = cvtpk(p0[6], p0[7]);
      unsigned b0 = cvtpk(p0[8], p0[9]), b1 = cvtpk(p0[10], p0[11]);
      unsigned b2 = cvtpk(p0[12], p0[13]), b3 = cvtpk(p0[14], p0[15]);
      swap32(a0, a2); swap32(a1, a3); swap32(b0, b2); swap32(b1, b3);
      bf16x8 pa0 = mk8(a0, a1, a2, a3);
      bf16x8 pa1 = mk8(b0, b1, b2, b3);
      __builtin_amdgcn_s_setprio(1);
#pragma unroll
      for (int et = 0; et < 4; ++et) {
        const int row = et * 32 + l31;
        bf16x8 v0 = *(const bf16x8*)(vb + (size_t)row * 64 + ((cbb + 0) & 7) * 8);
        bf16x8 v1 = *(const bf16x8*)(vb + (size_t)row * 64 + ((cbb + 2) & 7) * 8);
        o_acc[et] = mfma32(pa0, v0, o_acc[et]);
        o_acc[et] = mfma32(pa1, v1, o_acc[et]);
      }
      __builtin_amdgcn_s_setprio(0);
    }

    // ---- half 1: exp(s1) -> pack pa2,pa3 -> PV slots 2,3 (k 32..63)
    {
      float p1[16];
#pragma unroll
      for (int r = 0; r < 16; ++r) {
        const int sh = (r & 3) + 8 * (r >> 2);
        float x1 = s1[r] * CL2E;
        float t1 = ((mbh >> (sh + 32)) & 1) ? x1 : -60.0f;
        float e1 = rm ? t1 : 0.0f;
        p1[r] = __builtin_amdgcn_exp2f(e1);
        l_lane += p1[r];
      }
      unsigned c0 = cvtpk(p1[0], p1[1]), c1 = cvtpk(p1[2], p1[3]);
      unsigned c2 = cvtpk(p1[4], p1[5]), c3 = cvtpk(p1[6], p1[7]);
      unsigned d0 = cvtpk(p1[8], p1[9]), d1 = cvtpk(p1[10], p1[11]);
      unsigned d2 = cvtpk(p1[12], p1[13]), d3 = cvtpk(p1[14], p1[15]);
      swap32(c0, c2); swap32(c1, c3); swap32(d0, d2); swap32(d1, d3);
      bf16x8 pa2 = mk8(c0, c1, c2, c3);
      bf16x8 pa3 = mk8(d0, d1, d2, d3);
      __builtin_amdgcn_s_setprio(1);
#pragma unroll
      for (int et = 0; et < 4; ++et) {
        const int row = et * 32 + l31;
        bf16x8 v2 = *(const bf16x8*)(vb + (size_t)row * 64 + ((cbb + 4) & 7) * 8);
        bf16x8 v3 = *(const bf16x8*)(vb + (size_t)row * 64 + ((cbb + 6) & 7) * 8);
        o_acc[et] = mfma32(pa2, v2, o_acc[et]);
        o_acc[et] = mfma32(pa3, v3, o_acc[et]);
      }
      __builtin_amdgcn_s_setprio(0);
    }
  }

  // final l per q: lane + lane^32, broadcast via LDS for epilogue
  l_lane += __shfl_xor(l_lane, 32, 64);
  if (hi == 0) l_s[w * 32 + l31] = l_lane;
  __syncthreads();

  // epilogue: O/l, store. lane holds q = crow(r,hi), e = et*32 + l31
#pragma unroll
  for (int r = 0; r < 16; ++r) {
    const int ql = (r & 3) + 8 * (r >> 2) + 4 * hi;
    const float inv = 1.0f / l_s[w * 32 + ql];
    const int row = q0 + w * 32 + ql;
#pragma unroll
    for (int et = 0; et < 4; ++et) {
      const int col = h * HDIM + et * 32 + l31;
      O[((size_t)b * BN + row) * DD + col] = f2bf(o_acc[et][r] * inv);
    }
  }
}

// ---------------------------------------------------------------------------
// Workspace layout (bytes): total ~168 MB
//   x_bf @0 33554432 | wqkvT @33554432 6291456 | wfcT @39845888 2097152
//   q_bf @41943040 | k_bf @75497472 | vT_bf @109051904 | o_bf @142606336 (each 33554432)
// ---------------------------------------------------------------------------
extern "C" void kernel_launch(void* const* d_in, const int* in_sizes, int n_in,
                              void* d_out, int out_size, void* d_ws, size_t ws_size,
                              hipStream_t stream) {
  const float* x = (const float*)d_in[0];
  const int* xmask = (const int*)d_in[1];
  const float* Wq = (const float*)d_in[2];
  const float* bq = (const float*)d_in[3];
  const float* Wk = (const float*)d_in[4];
  const float* bk = (const float*)d_in[5];
  const float* Wv = (const float*)d_in[6];
  const float* bv = (const float*)d_in[7];
  const float* Wfc = (const float*)d_in[8];
  const float* bfc = (const float*)d_in[9];
  float* out = (float*)d_out;

  char* ws = (char*)d_ws;
  unsigned short* x_bf  = (unsigned short*)(ws);
  unsigned short* wqkvT = (unsigned short*)(ws + 33554432);
  unsigned short* wfcT  = (unsigned short*)(ws + 39845888);
  unsigned short* q_bf  = (unsigned short*)(ws + 41943040);
  unsigned short* k_bf  = (unsigned short*)(ws + 75497472);
  unsigned short* vT_bf = (unsigned short*)(ws + 109051904);
  unsigned short* o_bf  = (unsigned short*)(ws + 142606336);

  prep_kernel<<<dim3(20480), dim3(256), 0, stream>>>(x, Wq, Wk, Wv, Wfc, x_bf, wqkvT, wfcT);

  gemm128_kernel<0><<<dim3(3072), dim3(256), 0, stream>>>(
      x_bf, wqkvT, bq, bk, bv, q_bf, k_bf, vT_bf, nullptr);

  flash_attn_kernel<<<dim3(1024), dim3(256), 0, stream>>>(q_bf, k_bf, vT_bf, xmask, o_bf);

  gemm128_kernel<1><<<dim3(1024), dim3(256), 0, stream>>>(
      o_bf, wfcT, bfc, nullptr, nullptr, nullptr, nullptr, nullptr, out);
}